// Round 17
// baseline (242.079 us; speedup 1.0000x reference)
//
#include <hip/hip_runtime.h>
#include <stdint.h>

// YOLOv5 batched NMS — R17 ABLATION ROUND. Pipeline identical to R16
// (validated, 165us); adds two read-only probe kernels that execute
// prefixes of the nmsfull body with asm-keepalive (no global writes) to
// measure per-phase cost: probe_rs = rank+scatter; probe_rsm = +mask.
// greedy+flush = nmsfull - probe_rsm. Next round applies the targeted fix.

#define B       16
#define N       25200
#define NC      80
#define CAP     320
#define NSLOT   5
#define NPAIR   15
#define MAXDET  300
#define CONF_T  0.25f
#define FLATCAP 32768
#define PBLK    75
#define PROWS   336
#define LCAP    24
#define LSTR    25
#define ZWORDS  86272

typedef unsigned long long u64;
typedef unsigned int u32;

// ---------------------------------------------------------------- argmax
__global__ __launch_bounds__(256) void argmax_kernel(
    const float* __restrict__ pred, float4* __restrict__ box4,
    u64* __restrict__ rec, u32* __restrict__ zeroRegion)
{
    __shared__ float rowf[5440];
    int blk = blockIdx.x, t = threadIdx.x;

    int zidx = blk * 256 + t;
    if (zidx < ZWORDS) zeroRegion[zidx] = 0u;

    const float4* src4 = (const float4*)(pred + (size_t)blk * 5440);
    float4* dst4 = (float4*)rowf;
    #pragma unroll 3
    for (int i = t; i < 1360; i += 256) dst4[i] = src4[i];
    __syncthreads();

    int r = t >> 2, q = t & 3;
    int base = r * 85;
    float obj = rowf[base + 4];

    float bs = -1.0f; int bc = 0;
    int cbase = base + 5 + 20 * q;
    #pragma unroll 4
    for (int k = 0; k < 20; ++k) {
        float sc = __fmul_rn(rowf[cbase + k], obj);
        if (sc > bs) { bs = sc; bc = 20 * q + k; }
    }
    #pragma unroll
    for (int d = 1; d <= 2; d <<= 1) {
        float os = __shfl_xor(bs, d, 64);
        int   oc = __shfl_xor(bc, d, 64);
        if (os > bs || (os == bs && oc < bc)) { bs = os; bc = oc; }
    }

    if (q == 0) {
        float cx = rowf[base], cy = rowf[base + 1];
        float w = rowf[base + 2], h = rowf[base + 3];
        float hw = __fmul_rn(w, 0.5f), hh = __fmul_rn(h, 0.5f);
        float4 bb;
        bb.x = __fsub_rn(cx, hw); bb.y = __fsub_rn(cy, hh);
        bb.z = __fadd_rn(cx, hw); bb.w = __fadd_rn(cy, hh);
        int gid = blk * 64 + r;
        int img = gid / N, i = gid - img * N;
        box4[gid] = bb;
        bool valid = (obj > CONF_T) && (bs > CONF_T);
        rec[gid] = valid ? ((1ull << 63) | ((u64)__float_as_uint(bs) << 24)
                          | ((u64)bc << 16) | (u64)(u32)i)
                         : 0ull;
    }
}

// ---------------------------------------------------------------- bucket
__global__ __launch_bounds__(256) void bucket_kernel(
    const u64* __restrict__ rec, u64* __restrict__ bucket,
    int* __restrict__ cursor)
{
    __shared__ u64 list[NC * LSTR];
    __shared__ int lcnt[NC];
    int blk = blockIdx.x, t = threadIdx.x;
    int img = blk / PBLK, blkin = blk - img * PBLK;
    const u64* rbase = rec + (size_t)img * N + (size_t)blkin * PROWS;

    for (int c = t; c < NC; c += 256) lcnt[c] = 0;
    __syncthreads();

    #pragma unroll
    for (int pass = 0; pass < 2; ++pass) {
        int idx = pass * 256 + t;
        if (idx < PROWS) {
            u64 rc = rbase[idx];
            if (rc >> 63) {
                u32 cbits = (u32)(rc >> 24);
                int cls   = (int)((rc >> 16) & 0xFFu);
                u32 orig  = (u32)(rc & 0xFFFFu);
                int p = atomicAdd(&lcnt[cls], 1);
                if (p < LCAP)
                    list[cls * LSTR + p] =
                        ((u64)cbits << 32) | (u64)(u32)(~orig);
            }
        }
    }
    __syncthreads();

    if (t < NC) {
        int cnt = lcnt[t]; if (cnt > LCAP) cnt = LCAP;
        if (cnt > 0) {
            int slot = img * NC + t;
            int pos = atomicAdd(&cursor[slot * 16], cnt);
            u64* dst = bucket + (size_t)slot * CAP;
            for (int k = 0; k < cnt; ++k) {
                int pp = pos + k;
                if (pp < CAP) dst[pp] = list[t * LSTR + k];
            }
        }
    }
}

// ---------------------------------------------------------------- nms body
// PH=1: A-D (rank+scatter+gather), keepalive, no writes.
// PH=2: A-E (+transposed masks), keepalive, no writes.
// PH=3: full real kernel (greedy+flush+ghist writes).
template<int PH>
__device__ __forceinline__ void nms_body(
    const u64* __restrict__ bucket, const int* __restrict__ cursor,
    const float4* __restrict__ box4, u64* __restrict__ flat,
    int* __restrict__ imgCount, u32* __restrict__ ghist)
{
    __shared__ u64    keyL[CAP];
    __shared__ float4 bx[CAP];
    __shared__ float  ar[CAP];
    __shared__ u64    msk[NPAIR * 64];
    __shared__ u64    keptL[CAP];
    __shared__ int    sCnt, sPos;

    int bid = blockIdx.x;                  // img*NC + cls
    int img = bid / NC, cls = bid - img * NC;
    int tid = threadIdx.x, lane = tid & 63, wv = tid >> 6;
    int n = cursor[bid * 16]; if (n > CAP) n = CAP;
    int smax = (n + 63) >> 6;

    // A: zero-init
    for (int i = tid; i < CAP; i += 256) {
        keyL[i] = 0;
        bx[i] = make_float4(0.f, 0.f, 0.f, 0.f);
        ar[i] = 0.0f;
    }
    __syncthreads();

    // B: load keys
    int i0 = tid, i1 = tid + 256;
    u64 k0 = 0, k1 = 0;
    if (i0 < n) { k0 = bucket[(size_t)bid * CAP + i0]; keyL[i0] = k0; }
    if (i1 < n) { k1 = bucket[(size_t)bid * CAP + i1]; keyL[i1] = k1; }
    __syncthreads();

    // C: rank = #{keys greater}
    int r0 = 0, r1 = 0;
    #pragma unroll 4
    for (int j = 0; j < n; ++j) {
        u64 kj = keyL[j];
        r0 += (kj > k0) ? 1 : 0;
        r1 += (kj > k1) ? 1 : 0;
    }
    __syncthreads();

    // D: scatter to rank order + gather offset boxes + areas
    float off = __fmul_rn((float)cls, 4096.0f);
    if (i0 < n) {
        keyL[r0] = k0;
        u32 orig = ~((u32)k0);
        float4 b = box4[(size_t)img * N + orig];
        float4 c;
        c.x = __fadd_rn(b.x, off); c.y = __fadd_rn(b.y, off);
        c.z = __fadd_rn(b.z, off); c.w = __fadd_rn(b.w, off);
        bx[r0] = c;
        ar[r0] = __fmul_rn(__fsub_rn(c.z, c.x), __fsub_rn(c.w, c.y));
    }
    if (i1 < n) {
        keyL[r1] = k1;
        u32 orig = ~((u32)k1);
        float4 b = box4[(size_t)img * N + orig];
        float4 c;
        c.x = __fadd_rn(b.x, off); c.y = __fadd_rn(b.y, off);
        c.z = __fadd_rn(b.z, off); c.w = __fadd_rn(b.w, off);
        bx[r1] = c;
        ar[r1] = __fmul_rn(__fsub_rn(c.z, c.x), __fsub_rn(c.w, c.y));
    }
    __syncthreads();

    if constexpr (PH == 1) {
        // keepalive: sample rank/scatter results so A-D can't be DCE'd
        u64 acc = keyL[(tid * 37) % CAP]
                ^ ((u64)__float_as_uint(bx[(tid * 53) % CAP].x) << 8)
                ^ (u64)__float_as_uint(ar[(tid * 29) % CAP]);
        asm volatile("" :: "v"(acc));
        return;
    }

    // E: masks, TRANSPOSED (validated R16)
    const float cthr = 0.45f;
    const double M = ((double)cthr
                    + (double)__uint_as_float(__float_as_uint(cthr) + 1)) * 0.5;
    for (int p = wv; p < NPAIR; p += 4) {
        int s, w;
        if      (p < 5)  { w = 0; s = p;     }
        else if (p < 9)  { w = 1; s = p - 4; }
        else if (p < 12) { w = 2; s = p - 7; }
        else if (p < 14) { w = 3; s = p - 9; }
        else             { w = 4; s = 4;     }
        u32 wlo = 0, whi = 0;
        if (s < smax) {
            float4 ob = bx[(w << 6) + lane];
            float oa = ar[(w << 6) + lane];
            int jlim = n - (w << 6); if (jlim > 64) jlim = 64;
            u64 jmask = (jlim >= 64) ? ~0ull : ((1ull << jlim) - 1);
            int ilim = n - (s << 6); if (ilim > 64) ilim = 64;
            bool diag = (s == w);
            #pragma unroll 4
            for (int i = 0; i < ilim; ++i) {
                float4 mb = bx[(s << 6) + i];
                float ma = ar[(s << 6) + i];
                float ltx = fmaxf(mb.x, ob.x);
                float lty = fmaxf(mb.y, ob.y);
                float rbx = fminf(mb.z, ob.z);
                float rby = fminf(mb.w, ob.w);
                float wx  = fmaxf(__fsub_rn(rbx, ltx), 0.0f);
                float wy  = fmaxf(__fsub_rn(rby, lty), 0.0f);
                float inter = __fmul_rn(wx, wy);
                float denom = __fsub_rn(__fadd_rn(ma, oa), inter);
                u64 word = __ballot((double)inter > M * (double)denom);
                word &= jmask;
                if (diag) word &= (1ull << i) - 1;
                bool own = (lane == i);
                wlo = own ? (u32)word : wlo;
                whi = own ? (u32)(word >> 32) : whi;
            }
        }
        msk[p * 64 + lane] = ((u64)whi << 32) | wlo;
    }
    __syncthreads();

    if constexpr (PH == 2) {
        // keepalive: sample masks (and upstream) so A-E can't be DCE'd
        u64 acc = msk[(tid * 29) % (NPAIR * 64)]
                ^ keyL[(tid * 37) % CAP]
                ^ (u64)__float_as_uint(ar[(tid * 53) % CAP]);
        asm volatile("" :: "v"(acc));
        return;
    }

    // F: greedy on wave 0 (validated)
    if (wv == 0) {
        u32 aliveBits = 0;
        #pragma unroll
        for (int s = 0; s < NSLOT; ++s)
            if ((s << 6) + lane < n) aliveBits |= 1u << s;

        int cnt = 0;
        for (int s0 = 0; s0 < smax; ++s0) {
            u64 bl = __ballot((aliveBits >> s0) & 1u);
            if (!bl) continue;
            int o = (s0 == 0) ? 0 : (s0 == 1) ? 5 : (s0 == 2) ? 9
                  : (s0 == 3) ? 12 : 14;
            u64 cur0 = msk[(o                        ) * 64 + lane];
            u64 cur1 = msk[(o + (1 > s0 ? 1 - s0 : 0)) * 64 + lane];
            u64 cur2 = msk[(o + (2 > s0 ? 2 - s0 : 0)) * 64 + lane];
            u64 cur3 = msk[(o + (3 > s0 ? 3 - s0 : 0)) * 64 + lane];
            u64 cur4 = msk[(o + (4 > s0 ? 4 - s0 : 0)) * 64 + lane];
            u64 mykey = keyL[(s0 << 6) + lane];
            while (bl) {
                int wl = __ffsll((long long)bl) - 1;
                if (lane == wl) {
                    u32 orig = ~((u32)mykey);
                    keptL[cnt] = (mykey & 0xFFFFFFFF00000000ull)
                               | ((u64)(0x7FFFu - orig) << 16) | (u64)cls;
                }
                cnt++;
                u32 kill = (u32)((cur0 >> wl) & 1ull)
                         | ((u32)((cur1 >> wl) & 1ull) << 1)
                         | ((u32)((cur2 >> wl) & 1ull) << 2)
                         | ((u32)((cur3 >> wl) & 1ull) << 3)
                         | ((u32)((cur4 >> wl) & 1ull) << 4);
                aliveBits &= ~kill;
                if (lane == wl) aliveBits &= ~(1u << s0);
                bl = __ballot((aliveBits >> s0) & 1u);
            }
        }
        if (lane == 0) sCnt = cnt;
    }
    __syncthreads();

    // G: flush + fused histogram
    int cnt = sCnt;
    if (tid == 0) sPos = atomicAdd(&imgCount[img * 16], cnt);
    __syncthreads();
    int pos = sPos;
    for (int i = tid; i < cnt; i += 256) {
        u64 k = keptL[i];
        flat[(size_t)img * FLATCAP + pos + i] = k;
        float cf = __uint_as_float((u32)(k >> 32));
        int q = (int)__fmul_rn(cf, 4096.0f);
        if (q > 4095) q = 4095;
        atomicAdd(&ghist[img * 4096 + q], 1u);
    }
}

__global__ __launch_bounds__(256) void nmsfull_kernel(
    const u64* __restrict__ bucket, const int* __restrict__ cursor,
    const float4* __restrict__ box4, u64* __restrict__ flat,
    int* __restrict__ imgCount, u32* __restrict__ ghist)
{ nms_body<3>(bucket, cursor, box4, flat, imgCount, ghist); }

__global__ __launch_bounds__(256) void probe_rs(
    const u64* __restrict__ bucket, const int* __restrict__ cursor,
    const float4* __restrict__ box4, u64* __restrict__ flat,
    int* __restrict__ imgCount, u32* __restrict__ ghist)
{ nms_body<1>(bucket, cursor, box4, flat, imgCount, ghist); }

__global__ __launch_bounds__(256) void probe_rsm(
    const u64* __restrict__ bucket, const int* __restrict__ cursor,
    const float4* __restrict__ box4, u64* __restrict__ flat,
    int* __restrict__ imgCount, u32* __restrict__ ghist)
{ nms_body<2>(bucket, cursor, box4, flat, imgCount, ghist); }

// ---------------------------------------------------------------- final
__global__ __launch_bounds__(256) void final_kernel(
    const float4* __restrict__ box4, const u64* __restrict__ flat,
    const int* __restrict__ imgCount, const u32* __restrict__ ghist,
    float* __restrict__ out)
{
    int img = blockIdx.x;
    int tid = threadIdx.x;
    __shared__ u32 hist[4096];
    __shared__ u64 sel[1024];
    __shared__ u32 part[256];
    __shared__ int sB, sSel;

    int cnt = imgCount[img * 16]; if (cnt > FLATCAP) cnt = FLATCAP;
    const u64* lst = flat + (size_t)img * FLATCAP;

    for (int i = tid; i < 4096; i += 256) hist[i] = ghist[img * 4096 + i];
    if (tid == 0) { sB = -1; sSel = 0; }
    __syncthreads();

    u32 pt = 0;
    #pragma unroll
    for (int k2 = 0; k2 < 16; ++k2) pt += hist[tid * 16 + k2];
    part[tid] = pt;
    __syncthreads();
    u32 S = pt;
    for (int offn = 1; offn < 256; offn <<= 1) {
        u32 v = (tid + offn < 256) ? part[tid + offn] : 0;
        __syncthreads();
        S += v; part[tid] = S;
        __syncthreads();
    }
    u32 Snext = S - pt;
    if (S >= MAXDET && Snext < MAXDET) {
        u32 run = Snext;
        for (int k2 = 15; k2 >= 0; --k2) {
            u32 hgt = hist[tid * 16 + k2];
            run += hgt;
            if (run >= MAXDET) { sB = tid * 16 + k2; break; }
        }
    }
    __syncthreads();
    int Bq = sB;

    for (int i = tid; i < cnt; i += 256) {
        u64 k = lst[i];
        float cf = __uint_as_float((u32)(k >> 32));
        int q = (int)__fmul_rn(cf, 4096.0f);
        if (q > 4095) q = 4095;
        if (q >= Bq) {
            int p = atomicAdd(&sSel, 1);
            if (p < 1024) sel[p] = k;
        }
    }
    __syncthreads();
    int selCnt = sSel; if (selCnt > 1024) selCnt = 1024;
    for (int i = selCnt + tid; i < 1024; i += 256) sel[i] = 0;
    __syncthreads();

    u64 mine[4]; int rk[4];
    #pragma unroll
    for (int tt = 0; tt < 4; ++tt) { mine[tt] = sel[tid + 256 * tt]; rk[tt] = 0; }
    #pragma unroll 4
    for (int j = 0; j < selCnt; ++j) {
        u64 kj = sel[j];
        #pragma unroll
        for (int tt = 0; tt < 4; ++tt) rk[tt] += (kj > mine[tt]) ? 1 : 0;
    }
    int outCnt = selCnt < MAXDET ? selCnt : MAXDET;

    float* dets  = out + (size_t)img * MAXDET * 6;
    float* keeps = out + (size_t)B * MAXDET * 6 + (size_t)img * MAXDET;
    for (int r = tid; r < MAXDET; r += 256) {
        #pragma unroll
        for (int j = 0; j < 6; ++j) dets[r * 6 + j] = 0.0f;
        keeps[r] = 0.0f;
    }
    __syncthreads();
    #pragma unroll
    for (int tt = 0; tt < 4; ++tt) {
        int r = rk[tt];
        if (r < outCnt) {
            u64 k = mine[tt];
            float cf = __uint_as_float((u32)(k >> 32));
            int orig = 0x7FFF - (int)((k >> 16) & 0x7FFF);
            int cl   = (int)(k & 0xFFFF);
            float4 b = box4[(size_t)img * N + orig];
            dets[r * 6 + 0] = b.x; dets[r * 6 + 1] = b.y;
            dets[r * 6 + 2] = b.z; dets[r * 6 + 3] = b.w;
            dets[r * 6 + 4] = cf;  dets[r * 6 + 5] = (float)cl;
            keeps[r] = 1.0f;
        }
    }
}

// ---------------------------------------------------------------- launch
extern "C" void kernel_launch(void* const* d_in, const int* in_sizes, int n_in,
                              void* d_out, int out_size, void* d_ws, size_t ws_size,
                              hipStream_t stream)
{
    const float* pred = (const float*)d_in[0];
    float* out = (float*)d_out;
    char* ws = (char*)d_ws;

    int*    cursor   = (int*)ws;
    int*    imgCount = (int*)(ws + 81920);
    u32*    ghist    = (u32*)(ws + 82944);
    u64*    keys     = (u64*)(ws + 345088);
    float4* box4     = (float4*)(ws + 3621888);
    u64*    flat     = (u64*)(ws + 10073088);
    u64*    rec      = (u64*)(ws + 14267392);

    argmax_kernel <<<B * N / 64, 256, 0, stream>>>(pred, box4, rec, (u32*)ws);
    bucket_kernel <<<B * PBLK, 256, 0, stream>>>(rec, keys, cursor);
    nmsfull_kernel<<<B * NC, 256, 0, stream>>>(keys, cursor, box4, flat,
                                               imgCount, ghist);
    // read-only phase probes (instrumentation; no effect on outputs)
    probe_rs      <<<B * NC, 256, 0, stream>>>(keys, cursor, box4, flat,
                                               imgCount, ghist);
    probe_rsm     <<<B * NC, 256, 0, stream>>>(keys, cursor, box4, flat,
                                               imgCount, ghist);
    final_kernel  <<<B, 256, 0, stream>>>(box4, flat, imgCount, ghist, out);
}

// Round 18
// 128.102 us; speedup vs baseline: 1.8897x; 1.8897x over previous
//
#include <hip/hip_runtime.h>
#include <stdint.h>

// YOLOv5 batched NMS. B=16 images, N=25200 boxes, NC=80 classes.
// Per-class decomposition (cls*4096 offsets => cross-class IoU == 0).
// argmax:  PURE-STREAM pass; also zeroes the 345KB counter region.
// bucket:  rec array -> LDS per-class lists -> padded per-class atomics.
// nmsfull: FUSED rank+mask+greedy. R18: (a) pair->wave table reordered so
//          per-wave IoU rows are {150,150,128,128} not {192,...,86} at the
//          typical smax=4; (b) greedy = 3-STATE FIXPOINT (kept/dead/undec):
//          each pass decides every rank whose strictly-lower suppressors
//          are all decided == exactly the greedy kept set (induction on
//          rank); converges in ~chain-depth passes vs ~200 serial ballot
//          iterations; emit = parallel popcount-prefix compaction.
// final:   threshold bin (validated scan), collect, rank-by-count, emit.
//
// IoU predicate without div, bit-exact: RN(inter/denom) > 0.45f
// <=> (double)inter > M*(double)denom, M = midpoint(0.45f, nextafterf up).

#define B       16
#define N       25200
#define NC      80
#define CAP     320
#define NSLOT   5
#define NPAIR   15
#define MAXDET  300
#define CONF_T  0.25f
#define FLATCAP 32768
#define PBLK    75
#define PROWS   336
#define LCAP    24
#define LSTR    25
#define ZWORDS  86272

typedef unsigned long long u64;
typedef unsigned int u32;

// pair p -> (s,w), row-balanced across waves (p&3) for smax=4:
// rows/wave = {150,150,128,128}; s=4 pairs (rare, n>256) at p=10..14.
__device__ __constant__ const int PS_[NPAIR] = {0,1,1,2, 3,3,2,2, 3,3, 4,4,4,4,4};
__device__ __constant__ const int PW_[NPAIR] = {0,1,0,0, 0,1,1,2, 2,3, 0,1,2,3,4};

// ---------------------------------------------------------------- argmax
__global__ __launch_bounds__(256) void argmax_kernel(
    const float* __restrict__ pred, float4* __restrict__ box4,
    u64* __restrict__ rec, u32* __restrict__ zeroRegion)
{
    __shared__ float rowf[5440];
    int blk = blockIdx.x, t = threadIdx.x;

    int zidx = blk * 256 + t;
    if (zidx < ZWORDS) zeroRegion[zidx] = 0u;

    const float4* src4 = (const float4*)(pred + (size_t)blk * 5440);
    float4* dst4 = (float4*)rowf;
    #pragma unroll 3
    for (int i = t; i < 1360; i += 256) dst4[i] = src4[i];
    __syncthreads();

    int r = t >> 2, q = t & 3;
    int base = r * 85;
    float obj = rowf[base + 4];

    float bs = -1.0f; int bc = 0;
    int cbase = base + 5 + 20 * q;
    #pragma unroll 4
    for (int k = 0; k < 20; ++k) {
        float sc = __fmul_rn(rowf[cbase + k], obj);
        if (sc > bs) { bs = sc; bc = 20 * q + k; }
    }
    #pragma unroll
    for (int d = 1; d <= 2; d <<= 1) {
        float os = __shfl_xor(bs, d, 64);
        int   oc = __shfl_xor(bc, d, 64);
        if (os > bs || (os == bs && oc < bc)) { bs = os; bc = oc; }
    }

    if (q == 0) {
        float cx = rowf[base], cy = rowf[base + 1];
        float w = rowf[base + 2], h = rowf[base + 3];
        float hw = __fmul_rn(w, 0.5f), hh = __fmul_rn(h, 0.5f);
        float4 bb;
        bb.x = __fsub_rn(cx, hw); bb.y = __fsub_rn(cy, hh);
        bb.z = __fadd_rn(cx, hw); bb.w = __fadd_rn(cy, hh);
        int gid = blk * 64 + r;
        int img = gid / N, i = gid - img * N;
        box4[gid] = bb;
        bool valid = (obj > CONF_T) && (bs > CONF_T);
        rec[gid] = valid ? ((1ull << 63) | ((u64)__float_as_uint(bs) << 24)
                          | ((u64)bc << 16) | (u64)(u32)i)
                         : 0ull;
    }
}

// ---------------------------------------------------------------- bucket
__global__ __launch_bounds__(256) void bucket_kernel(
    const u64* __restrict__ rec, u64* __restrict__ bucket,
    int* __restrict__ cursor)
{
    __shared__ u64 list[NC * LSTR];
    __shared__ int lcnt[NC];
    int blk = blockIdx.x, t = threadIdx.x;
    int img = blk / PBLK, blkin = blk - img * PBLK;
    const u64* rbase = rec + (size_t)img * N + (size_t)blkin * PROWS;

    for (int c = t; c < NC; c += 256) lcnt[c] = 0;
    __syncthreads();

    #pragma unroll
    for (int pass = 0; pass < 2; ++pass) {
        int idx = pass * 256 + t;
        if (idx < PROWS) {
            u64 rc = rbase[idx];
            if (rc >> 63) {
                u32 cbits = (u32)(rc >> 24);
                int cls   = (int)((rc >> 16) & 0xFFu);
                u32 orig  = (u32)(rc & 0xFFFFu);
                int p = atomicAdd(&lcnt[cls], 1);
                if (p < LCAP)
                    list[cls * LSTR + p] =
                        ((u64)cbits << 32) | (u64)(u32)(~orig);
            }
        }
    }
    __syncthreads();

    if (t < NC) {
        int cnt = lcnt[t]; if (cnt > LCAP) cnt = LCAP;
        if (cnt > 0) {
            int slot = img * NC + t;
            int pos = atomicAdd(&cursor[slot * 16], cnt);
            u64* dst = bucket + (size_t)slot * CAP;
            for (int k = 0; k < cnt; ++k) {
                int pp = pos + k;
                if (pp < CAP) dst[pp] = list[t * LSTR + k];
            }
        }
    }
}

// ---------------------------------------------------------------- nmsfull
__global__ __launch_bounds__(256) void nmsfull_kernel(
    const u64* __restrict__ bucket, const int* __restrict__ cursor,
    const float4* __restrict__ box4, u64* __restrict__ flat,
    int* __restrict__ imgCount, u32* __restrict__ ghist)
{
    __shared__ u64    keyL[CAP];
    __shared__ float4 bx[CAP];
    __shared__ float  ar[CAP];
    __shared__ u64    msk[NPAIR * 64];
    __shared__ u64    keptL[CAP];
    __shared__ int    sCnt, sPos;

    int bid = blockIdx.x;                  // img*NC + cls
    int img = bid / NC, cls = bid - img * NC;
    int tid = threadIdx.x, lane = tid & 63, wv = tid >> 6;
    int n = cursor[bid * 16]; if (n > CAP) n = CAP;
    int smax = (n + 63) >> 6;

    // A: zero-init
    for (int i = tid; i < CAP; i += 256) {
        keyL[i] = 0;
        bx[i] = make_float4(0.f, 0.f, 0.f, 0.f);
        ar[i] = 0.0f;
    }
    __syncthreads();

    // B: load keys
    int i0 = tid, i1 = tid + 256;
    u64 k0 = 0, k1 = 0;
    if (i0 < n) { k0 = bucket[(size_t)bid * CAP + i0]; keyL[i0] = k0; }
    if (i1 < n) { k1 = bucket[(size_t)bid * CAP + i1]; keyL[i1] = k1; }
    __syncthreads();

    // C: rank = #{keys greater} (keys unique -> permutation)
    int r0 = 0, r1 = 0;
    #pragma unroll 4
    for (int j = 0; j < n; ++j) {
        u64 kj = keyL[j];
        r0 += (kj > k0) ? 1 : 0;
        r1 += (kj > k1) ? 1 : 0;
    }
    __syncthreads();

    // D: scatter to rank order + gather offset boxes + areas
    float off = __fmul_rn((float)cls, 4096.0f);
    if (i0 < n) {
        keyL[r0] = k0;
        u32 orig = ~((u32)k0);
        float4 b = box4[(size_t)img * N + orig];
        float4 c;
        c.x = __fadd_rn(b.x, off); c.y = __fadd_rn(b.y, off);
        c.z = __fadd_rn(b.z, off); c.w = __fadd_rn(b.w, off);
        bx[r0] = c;
        ar[r0] = __fmul_rn(__fsub_rn(c.z, c.x), __fsub_rn(c.w, c.y));
    }
    if (i1 < n) {
        keyL[r1] = k1;
        u32 orig = ~((u32)k1);
        float4 b = box4[(size_t)img * N + orig];
        float4 c;
        c.x = __fadd_rn(b.x, off); c.y = __fadd_rn(b.y, off);
        c.z = __fadd_rn(b.z, off); c.w = __fadd_rn(b.w, off);
        bx[r1] = c;
        ar[r1] = __fmul_rn(__fsub_rn(c.z, c.x), __fsub_rn(c.w, c.y));
    }
    __syncthreads();

    // E: transposed masks (validated R16), row-balanced pair table
    const float cthr = 0.45f;
    const double M = ((double)cthr
                    + (double)__uint_as_float(__float_as_uint(cthr) + 1)) * 0.5;
    #pragma unroll
    for (int p = 0; p < NPAIR; ++p) {
        if ((p & 3) != wv) continue;       // wave-uniform; p compile-time
        const int s = PS_[p], w = PW_[p];
        u32 wlo = 0, whi = 0;
        if (s < smax) {
            float4 ob = bx[(w << 6) + lane];
            float oa = ar[(w << 6) + lane];
            int jlim = n - (w << 6); if (jlim > 64) jlim = 64;
            u64 jmask = (jlim >= 64) ? ~0ull : ((1ull << jlim) - 1);
            int ilim = n - (s << 6); if (ilim > 64) ilim = 64;
            bool diag = (s == w);
            #pragma unroll 4
            for (int i = 0; i < ilim; ++i) {
                float4 mb = bx[(s << 6) + i];
                float ma = ar[(s << 6) + i];
                float ltx = fmaxf(mb.x, ob.x);
                float lty = fmaxf(mb.y, ob.y);
                float rbx = fminf(mb.z, ob.z);
                float rby = fminf(mb.w, ob.w);
                float wx  = fmaxf(__fsub_rn(rbx, ltx), 0.0f);
                float wy  = fmaxf(__fsub_rn(rby, lty), 0.0f);
                float inter = __fmul_rn(wx, wy);
                float denom = __fsub_rn(__fadd_rn(ma, oa), inter);
                u64 word = __ballot((double)inter > M * (double)denom);
                word &= jmask;
                if (diag) word &= (1ull << i) - 1;
                bool own = (lane == i);
                wlo = own ? (u32)word : wlo;
                whi = own ? (u32)(word >> 32) : whi;
            }
        }
        msk[p * 64 + lane] = ((u64)whi << 32) | wlo;
    }
    __syncthreads();

    // F: greedy as 3-state FIXPOINT on wave 0.
    // sup[p] = strictly-lower-rank suppressors of rank PS_[p]*64+lane in
    // slot PW_[p]. kept[x] <=> alive[x] and sup[x] ∩ kept = ∅ (== greedy
    // kept set, by induction on rank). Each pass decides all ranks whose
    // suppressors are fully decided; min undecided always resolves.
    if (wv == 0) {
        u64 sup[NPAIR];
        #pragma unroll
        for (int p = 0; p < NPAIR; ++p) sup[p] = msk[p * 64 + lane];

        u64 U[NSLOT], K[NSLOT];
        #pragma unroll
        for (int s = 0; s < NSLOT; ++s) {
            U[s] = __ballot((s << 6) + lane < n);
            K[s] = 0;
        }

        for (int pass = 0; pass < CAP; ++pass) {
            u64 accK[NSLOT], accU[NSLOT];
            #pragma unroll
            for (int s = 0; s < NSLOT; ++s) { accK[s] = 0; accU[s] = 0; }
            #pragma unroll
            for (int p = 0; p < NPAIR; ++p) {
                accK[PS_[p]] |= sup[p] & K[PW_[p]];
                accU[PS_[p]] |= sup[p] & U[PW_[p]];
            }
            #pragma unroll
            for (int s = 0; s < NSLOT; ++s) {
                bool myU = (U[s] >> lane) & 1;
                bool dead = myU && (accK[s] != 0);
                bool kept = myU && (accK[s] == 0) && (accU[s] == 0);
                u64 kb = __ballot(kept);
                u64 db = __ballot(dead);
                K[s] |= kb;
                U[s] &= ~(kb | db);
            }
            if ((U[0] | U[1] | U[2] | U[3] | U[4]) == 0) break;
        }

        // emit: parallel popcount-prefix compaction (slot-major rank order)
        int cnt = 0;
        #pragma unroll
        for (int s = 0; s < NSLOT; ++s) cnt += __popcll(K[s]);
        int basep = 0;
        #pragma unroll
        for (int s = 0; s < NSLOT; ++s) {
            if ((K[s] >> lane) & 1) {
                int pos = basep + __popcll(K[s] & ((1ull << lane) - 1));
                u64 mykey = keyL[(s << 6) + lane];
                u32 orig = ~((u32)mykey);
                keptL[pos] = (mykey & 0xFFFFFFFF00000000ull)
                           | ((u64)(0x7FFFu - orig) << 16) | (u64)cls;
            }
            basep += __popcll(K[s]);
        }
        if (lane == 0) sCnt = cnt;
    }
    __syncthreads();

    // G: flush kept keys (padded per-image atomic) + fused histogram
    int cnt = sCnt;
    if (tid == 0) sPos = atomicAdd(&imgCount[img * 16], cnt);
    __syncthreads();
    int pos = sPos;
    for (int i = tid; i < cnt; i += 256) {
        u64 k = keptL[i];
        flat[(size_t)img * FLATCAP + pos + i] = k;
        float cf = __uint_as_float((u32)(k >> 32));
        int q = (int)__fmul_rn(cf, 4096.0f);
        if (q > 4095) q = 4095;
        atomicAdd(&ghist[img * 4096 + q], 1u);
    }
}

// ---------------------------------------------------------------- final
__global__ __launch_bounds__(256) void final_kernel(
    const float4* __restrict__ box4, const u64* __restrict__ flat,
    const int* __restrict__ imgCount, const u32* __restrict__ ghist,
    float* __restrict__ out)
{
    int img = blockIdx.x;
    int tid = threadIdx.x;
    __shared__ u32 hist[4096];
    __shared__ u64 sel[1024];
    __shared__ u32 part[256];
    __shared__ int sB, sSel;

    int cnt = imgCount[img * 16]; if (cnt > FLATCAP) cnt = FLATCAP;
    const u64* lst = flat + (size_t)img * FLATCAP;

    for (int i = tid; i < 4096; i += 256) hist[i] = ghist[img * 4096 + i];
    if (tid == 0) { sB = -1; sSel = 0; }
    __syncthreads();

    u32 pt = 0;
    #pragma unroll
    for (int k2 = 0; k2 < 16; ++k2) pt += hist[tid * 16 + k2];
    part[tid] = pt;
    __syncthreads();
    u32 S = pt;
    for (int offn = 1; offn < 256; offn <<= 1) {
        u32 v = (tid + offn < 256) ? part[tid + offn] : 0;
        __syncthreads();
        S += v; part[tid] = S;
        __syncthreads();
    }
    u32 Snext = S - pt;
    if (S >= MAXDET && Snext < MAXDET) {
        u32 run = Snext;
        for (int k2 = 15; k2 >= 0; --k2) {
            u32 hgt = hist[tid * 16 + k2];
            run += hgt;
            if (run >= MAXDET) { sB = tid * 16 + k2; break; }
        }
    }
    __syncthreads();
    int Bq = sB;

    for (int i = tid; i < cnt; i += 256) {
        u64 k = lst[i];
        float cf = __uint_as_float((u32)(k >> 32));
        int q = (int)__fmul_rn(cf, 4096.0f);
        if (q > 4095) q = 4095;
        if (q >= Bq) {
            int p = atomicAdd(&sSel, 1);
            if (p < 1024) sel[p] = k;
        }
    }
    __syncthreads();
    int selCnt = sSel; if (selCnt > 1024) selCnt = 1024;
    for (int i = selCnt + tid; i < 1024; i += 256) sel[i] = 0;
    __syncthreads();

    u64 mine[4]; int rk[4];
    #pragma unroll
    for (int tt = 0; tt < 4; ++tt) { mine[tt] = sel[tid + 256 * tt]; rk[tt] = 0; }
    #pragma unroll 4
    for (int j = 0; j < selCnt; ++j) {
        u64 kj = sel[j];
        #pragma unroll
        for (int tt = 0; tt < 4; ++tt) rk[tt] += (kj > mine[tt]) ? 1 : 0;
    }
    int outCnt = selCnt < MAXDET ? selCnt : MAXDET;

    float* dets  = out + (size_t)img * MAXDET * 6;
    float* keeps = out + (size_t)B * MAXDET * 6 + (size_t)img * MAXDET;
    for (int r = tid; r < MAXDET; r += 256) {
        #pragma unroll
        for (int j = 0; j < 6; ++j) dets[r * 6 + j] = 0.0f;
        keeps[r] = 0.0f;
    }
    __syncthreads();
    #pragma unroll
    for (int tt = 0; tt < 4; ++tt) {
        int r = rk[tt];
        if (r < outCnt) {
            u64 k = mine[tt];
            float cf = __uint_as_float((u32)(k >> 32));
            int orig = 0x7FFF - (int)((k >> 16) & 0x7FFF);
            int cl   = (int)(k & 0xFFFF);
            float4 b = box4[(size_t)img * N + orig];
            dets[r * 6 + 0] = b.x; dets[r * 6 + 1] = b.y;
            dets[r * 6 + 2] = b.z; dets[r * 6 + 3] = b.w;
            dets[r * 6 + 4] = cf;  dets[r * 6 + 5] = (float)cl;
            keeps[r] = 1.0f;
        }
    }
}

// ---------------------------------------------------------------- launch
extern "C" void kernel_launch(void* const* d_in, const int* in_sizes, int n_in,
                              void* d_out, int out_size, void* d_ws, size_t ws_size,
                              hipStream_t stream)
{
    const float* pred = (const float*)d_in[0];
    float* out = (float*)d_out;
    char* ws = (char*)d_ws;

    int*    cursor   = (int*)ws;
    int*    imgCount = (int*)(ws + 81920);
    u32*    ghist    = (u32*)(ws + 82944);
    u64*    keys     = (u64*)(ws + 345088);
    float4* box4     = (float4*)(ws + 3621888);
    u64*    flat     = (u64*)(ws + 10073088);
    u64*    rec      = (u64*)(ws + 14267392);

    argmax_kernel <<<B * N / 64, 256, 0, stream>>>(pred, box4, rec, (u32*)ws);
    bucket_kernel <<<B * PBLK, 256, 0, stream>>>(rec, keys, cursor);
    nmsfull_kernel<<<B * NC, 256, 0, stream>>>(keys, cursor, box4, flat,
                                               imgCount, ghist);
    final_kernel  <<<B, 256, 0, stream>>>(box4, flat, imgCount, ghist, out);
}